// Round 12
// baseline (667.189 us; speedup 1.0000x reference)
//
#include <hip/hip_runtime.h>

#define BB 512
#define TT 1024
#define KK 48
#define NINF (-1e30f)

__device__ __forceinline__ float rfirst(float v) {
    return __int_as_float(__builtin_amdgcn_readfirstlane(__float_as_int(v)));
}

// ============================ shared scan macros ============================
// forward step (exp domain): 1 ds_write + 12 uniform ds_read_b128 + 48 fma
#define FSTEP_BODY(S4, RENORM, ES)                                           \
    {                                                                        \
        float z0 = 0.f, z1 = 0.f, z2 = 0.f, z3 = 0.f;                        \
        float z4 = 0.f, z5 = 0.f, z6 = 0.f, z7 = 0.f;                        \
        _Pragma("unroll")                                                    \
        for (int q_ = 0; q_ < 6; ++q_) {                                     \
            float4 v0 = S4[2 * q_], v1 = S4[2 * q_ + 1];                     \
            z0 = fmaf(v0.x, eTc[8 * q_ + 0], z0);                            \
            z1 = fmaf(v0.y, eTc[8 * q_ + 1], z1);                            \
            z2 = fmaf(v0.z, eTc[8 * q_ + 2], z2);                            \
            z3 = fmaf(v0.w, eTc[8 * q_ + 3], z3);                            \
            z4 = fmaf(v1.x, eTc[8 * q_ + 4], z4);                            \
            z5 = fmaf(v1.y, eTc[8 * q_ + 5], z5);                            \
            z6 = fmaf(v1.z, eTc[8 * q_ + 6], z6);                            \
            z7 = fmaf(v1.w, eTc[8 * q_ + 7], z7);                            \
        }                                                                    \
        p = (((z0 + z1) + (z2 + z3)) + ((z4 + z5) + (z6 + z7)))              \
            * __expf(ES);                                                    \
        if (RENORM) {                                                        \
            float m_ = rfirst(p);                                            \
            p *= __frcp_rn(m_);                                              \
            C += __logf(m_);                                                 \
        }                                                                    \
    }

// viterbi max phase: broadcast + add + exact max tree + recurrence
#define MAXPHASE_BODY(SB, S4, X, MV, ES)                                     \
    {                                                                        \
        SB[lane] = av;                 /* DS in-order: no barrier needed */  \
        _Pragma("unroll")                                                    \
        for (int q_ = 0; q_ < 12; ++q_) {                                    \
            float4 v_ = S4[q_];                                              \
            X[4 * q_ + 0] = v_.x + Tc[4 * q_ + 0];                           \
            X[4 * q_ + 1] = v_.y + Tc[4 * q_ + 1];                           \
            X[4 * q_ + 2] = v_.z + Tc[4 * q_ + 2];                           \
            X[4 * q_ + 3] = v_.w + Tc[4 * q_ + 3];                           \
        }                                                                    \
        float l1[16];                                                        \
        _Pragma("unroll")                                                    \
        for (int q_ = 0; q_ < 16; ++q_)                                      \
            l1[q_] = fmaxf(fmaxf(X[3 * q_], X[3 * q_ + 1]), X[3 * q_ + 2]);  \
        float l2[6];                                                         \
        _Pragma("unroll")                                                    \
        for (int q_ = 0; q_ < 5; ++q_)                                       \
            l2[q_] = fmaxf(fmaxf(l1[3 * q_], l1[3 * q_ + 1]),                \
                           l1[3 * q_ + 2]);                                  \
        l2[5] = l1[15];                                                      \
        MV = fmaxf(fmaxf(fmaxf(l2[0], l2[1]), l2[2]),                        \
                   fmaxf(fmaxf(l2[3], l2[4]), l2[5]));                       \
        av = MV + (ES);                                                      \
    }

// first-occurrence argmax, VGPR-pure: key_i = bits(x_i - M) | i
#define ARGPHASE_BODY(X, MV, STORE_STMT)                                     \
    {                                                                        \
        unsigned u[KK];                                                      \
        _Pragma("unroll")                                                    \
        for (int i_ = 0; i_ < KK; ++i_)                                      \
            u[i_] = (unsigned)__float_as_int(X[i_] - MV) | (unsigned)i_;     \
        unsigned m1[16];                                                     \
        _Pragma("unroll")                                                    \
        for (int q_ = 0; q_ < 16; ++q_)                                      \
            m1[q_] = min(min(u[3 * q_], u[3 * q_ + 1]), u[3 * q_ + 2]);      \
        unsigned m2[6];                                                      \
        _Pragma("unroll")                                                    \
        for (int q_ = 0; q_ < 5; ++q_)                                       \
            m2[q_] = min(min(m1[3 * q_], m1[3 * q_ + 1]), m1[3 * q_ + 2]);   \
        m2[5] = m1[15];                                                      \
        unsigned bi = min(min(min(m2[0], m2[1]), m2[2]),                     \
                          min(min(m2[3], m2[4]), m2[5]));                    \
        STORE_STMT;                                                          \
    }

// ===================== FAST kernel: bp in global scratch ====================
// 128 blocks x 512 threads: 4 batches/block, 8 waves/CU => 2 waves/SIMD.
// Per batch: wave role 0 = forward, role 1 = viterbi. LDS ~6 KB only.
__global__ __launch_bounds__(512, 1) void crf_fast(
    const float* __restrict__ em, const int* __restrict__ tags,
    const float* __restrict__ st, const float* __restrict__ en,
    const float* __restrict__ tr, float* __restrict__ out,
    float* __restrict__ wsl, unsigned char* __restrict__ gbp)
{
    __shared__ unsigned char s_path[4][TT];
    __shared__ float s_avb[8][64];

    const int tid  = threadIdx.x;
    const int lane = tid & 63;
    const int wid  = tid >> 6;
    const int q    = wid >> 1;      // batch slot in block
    const int role = wid & 1;       // 0 = forward, 1 = viterbi
    const int b    = blockIdx.x * 4 + q;

    const float* emb = em + (size_t)b * TT * KK;
    const int*   tgb = tags + (size_t)b * TT;

    int cnt = 0;
    for (int t = lane; t < TT; t += 64) cnt += (tgb[t] > -1) ? 1 : 0;
#pragma unroll
    for (int off = 32; off >= 1; off >>= 1) cnt += __shfl_xor(cnt, off);
    const int len = cnt;  // >= 1

    const bool act = lane < KK;
    const int  jj  = act ? lane : (KK - 1);   // lanes 48-63 mirror lane 47
    const int  S   = len - 1;

    float* sb = &s_avb[wid][0];
    const float4* S4 = (const float4*)sb;

    if (role == 0) {
        // ---- gold path score ----
        float sc = 0.f;
        for (int t = lane; t < len; t += 64) {
            int tg = tgb[t];
            sc += emb[t * KK + tg];
            if (t > 0) sc += tr[tgb[t - 1] * KK + tg];
        }
#pragma unroll
        for (int off = 32; off >= 1; off >>= 1) sc += __shfl_xor(sc, off);
        const float score = sc + st[tgb[0]] + en[tgb[len - 1]];

        // ---- forward scan, exp domain ----
        float eTc[KK];
#pragma unroll
        for (int i = 0; i < KK; ++i) eTc[i] = __expf(tr[i * KK + jj]);

        float a0 = st[jj] + emb[jj];
        float C  = rfirst(a0);
        float p  = __expf(a0 - C);

        float e[2];
        {
            int t1 = (1 < len) ? 1 : (len - 1);
            int t2 = (2 < len) ? 2 : (len - 1);
            e[1] = emb[(size_t)t1 * KK + jj];
            e[0] = emb[(size_t)t2 * KK + jj];
        }

#define FSTEP(t_, RENORM) {                                                  \
        const float eS = e[(t_) & 1];                                        \
        sb[lane] = p;                                                        \
        FSTEP_BODY(S4, RENORM, eS)                                           \
        int tn = (t_) + 2; tn = (tn < len) ? tn : (len - 1);                 \
        e[(t_) & 1] = emb[(size_t)tn * KK + jj];                             \
    }
        {
            int t = 1;
            for (; t + 4 <= S + 1; t += 4) {
                FSTEP(t, 0) FSTEP(t + 1, 0) FSTEP(t + 2, 0) FSTEP(t + 3, 1)
            }
            for (; t <= S; ++t) FSTEP(t, 1)
        }
#undef FSTEP

        float y = act ? (p * __expf(en[jj])) : 0.f;
#pragma unroll
        for (int off = 32; off >= 1; off >>= 1) y += __shfl_xor(y, off);
        float logz = C + __logf(y);
        if (lane == 0) wsl[b] = score - logz;
    } else {
        // ---- viterbi (bit-exact) ----
        float Tc[KK];
#pragma unroll
        for (int i = 0; i < KK; ++i) Tc[i] = tr[i * KK + jj];

        float av = st[jj] + emb[jj];

        float e[2];
        {
            int t1 = (1 < len) ? 1 : (len - 1);
            int t2 = (2 < len) ? 2 : (len - 1);
            e[1] = emb[(size_t)t1 * KK + jj];
            e[0] = emb[(size_t)t2 * KK + jj];
        }

        float xA[KK], xB[KK];
        float MA = 0.f, MB = 0.f;
        unsigned char* bpb = gbp + (size_t)b * TT * KK;

#define MAXPHASE(X, MV, t_) {                                                \
        const float eS = e[(t_) & 1];                                        \
        MAXPHASE_BODY(sb, S4, X, MV, eS)                                     \
        int tn = (t_) + 2; tn = (tn < len) ? tn : (len - 1);                 \
        e[(t_) & 1] = emb[(size_t)tn * KK + jj];                             \
    }
#define ARGPHASE(X, MV, t_) \
        ARGPHASE_BODY(X, MV, bpb[(size_t)(t_) * KK + jj] = (unsigned char)bi)

        if (S >= 1) {
            int t = 1;
            MAXPHASE(xA, MA, 1)
            while (t + 2 <= S) {
                MAXPHASE(xB, MB, t + 1)
                ARGPHASE(xA, MA, t)
                MAXPHASE(xA, MA, t + 2)
                ARGPHASE(xB, MB, t + 1)
                t += 2;
            }
            if (t + 1 <= S) {
                MAXPHASE(xB, MB, t + 1)
                ARGPHASE(xA, MA, t)
                ARGPHASE(xB, MB, t + 1)
            } else {
                ARGPHASE(xA, MA, t)
            }
        }
#undef MAXPHASE
#undef ARGPHASE

        // best last tag
        float v = act ? (av + en[jj]) : NINF;
        float M = v;
#pragma unroll
        for (int off = 32; off >= 1; off >>= 1) M = fmaxf(M, __shfl_xor(M, off));
        unsigned long long msk = __ballot(v == M);
        int cur = __ffsll(msk) - 1;
        s_path[q][len - 1] = (unsigned char)cur;

        // drain bp stores so our own reads see them, then backtrack from
        // global (L2-resident; 8 independent row loads per serial batch).
        asm volatile("s_waitcnt vmcnt(0)" ::: "memory");
        int t = len - 1;
        while (t >= 1) {
            const int n = (t < 8) ? t : 8;
            unsigned r[8];
#pragma unroll
            for (int k = 0; k < 8; ++k)
                r[k] = (k < n) ? (unsigned)bpb[(size_t)(t - k) * KK + jj] : 0u;
#pragma unroll
            for (int k = 0; k < 8; ++k) {
                if (k < n) {
                    cur = __builtin_amdgcn_readlane((int)r[k], cur);
                    if (lane == 0) s_path[q][t - k - 1] = (unsigned char)cur;
                }
            }
            t -= n;
        }

        float* ob = out + 1 + (size_t)b * TT;
        for (int tt = lane; tt < TT; tt += 64)
            ob[tt] = (tt < len) ? (float)s_path[q][tt] : -1.0f;
    }
}

// ================== FALLBACK kernel: R9 verbatim (bp in LDS) ================
__global__ __launch_bounds__(128, 1) void crf_main(
    const float* __restrict__ em, const int* __restrict__ tags,
    const float* __restrict__ st, const float* __restrict__ en,
    const float* __restrict__ tr, float* __restrict__ out,
    float* __restrict__ ws)
{
    __shared__ unsigned char s_bp[TT * KK];
    __shared__ unsigned char s_path[TT];
    __shared__ float s_avb[2][64];

    const int b    = blockIdx.x;
    const int tid  = threadIdx.x;
    const int lane = tid & 63;
    const int wid  = tid >> 6;

    const float* emb = em + (size_t)b * TT * KK;
    const int*   tgb = tags + (size_t)b * TT;

    int cnt = 0;
    for (int t = lane; t < TT; t += 64) cnt += (tgb[t] > -1) ? 1 : 0;
#pragma unroll
    for (int off = 32; off >= 1; off >>= 1) cnt += __shfl_xor(cnt, off);
    const int len = cnt;

    const bool act = lane < KK;
    const int  jj  = act ? lane : (KK - 1);
    const int  S   = len - 1;

    if (wid == 0) {
        float sc = 0.f;
        for (int t = lane; t < len; t += 64) {
            int tg = tgb[t];
            sc += emb[t * KK + tg];
            if (t > 0) sc += tr[tgb[t - 1] * KK + tg];
        }
#pragma unroll
        for (int off = 32; off >= 1; off >>= 1) sc += __shfl_xor(sc, off);
        const float score = sc + st[tgb[0]] + en[tgb[len - 1]];

        float eTc[KK];
#pragma unroll
        for (int i = 0; i < KK; ++i) eTc[i] = __expf(tr[i * KK + jj]);

        float a0 = st[jj] + emb[jj];
        float C  = rfirst(a0);
        float p  = __expf(a0 - C);

        float* sb = &s_avb[0][0];
        const float4* S4 = (const float4*)sb;

        float e[2];
        {
            int t1 = (1 < len) ? 1 : (len - 1);
            int t2 = (2 < len) ? 2 : (len - 1);
            e[1] = emb[(size_t)t1 * KK + jj];
            e[0] = emb[(size_t)t2 * KK + jj];
        }

#define FSTEP(t_, RENORM) {                                                  \
        const float eS = e[(t_) & 1];                                        \
        sb[lane] = p;                                                        \
        FSTEP_BODY(S4, RENORM, eS)                                           \
        int tn = (t_) + 2; tn = (tn < len) ? tn : (len - 1);                 \
        e[(t_) & 1] = emb[(size_t)tn * KK + jj];                             \
    }
        {
            int t = 1;
            for (; t + 4 <= S + 1; t += 4) {
                FSTEP(t, 0) FSTEP(t + 1, 0) FSTEP(t + 2, 0) FSTEP(t + 3, 1)
            }
            for (; t <= S; ++t) FSTEP(t, 1)
        }
#undef FSTEP

        float y = act ? (p * __expf(en[jj])) : 0.f;
#pragma unroll
        for (int off = 32; off >= 1; off >>= 1) y += __shfl_xor(y, off);
        float logz = C + __logf(y);
        if (lane == 0) ws[b] = score - logz;
    } else {
        float Tc[KK];
#pragma unroll
        for (int i = 0; i < KK; ++i) Tc[i] = tr[i * KK + jj];

        float av = st[jj] + emb[jj];

        float* sb = &s_avb[1][0];
        const float4* S4 = (const float4*)sb;

        float e[2];
        {
            int t1 = (1 < len) ? 1 : (len - 1);
            int t2 = (2 < len) ? 2 : (len - 1);
            e[1] = emb[(size_t)t1 * KK + jj];
            e[0] = emb[(size_t)t2 * KK + jj];
        }

        float xA[KK], xB[KK];
        float MA = 0.f, MB = 0.f;

#define MAXPHASE(X, MV, t_) {                                                \
        const float eS = e[(t_) & 1];                                        \
        MAXPHASE_BODY(sb, S4, X, MV, eS)                                     \
        int tn = (t_) + 2; tn = (tn < len) ? tn : (len - 1);                 \
        e[(t_) & 1] = emb[(size_t)tn * KK + jj];                             \
    }
#define ARGPHASE(X, MV, t_) \
        ARGPHASE_BODY(X, MV, s_bp[(size_t)(t_) * KK + jj] = (unsigned char)bi)

        if (S >= 1) {
            int t = 1;
            MAXPHASE(xA, MA, 1)
            while (t + 2 <= S) {
                MAXPHASE(xB, MB, t + 1)
                ARGPHASE(xA, MA, t)
                MAXPHASE(xA, MA, t + 2)
                ARGPHASE(xB, MB, t + 1)
                t += 2;
            }
            if (t + 1 <= S) {
                MAXPHASE(xB, MB, t + 1)
                ARGPHASE(xA, MA, t)
                ARGPHASE(xB, MB, t + 1)
            } else {
                ARGPHASE(xA, MA, t)
            }
        }
#undef MAXPHASE
#undef ARGPHASE

        float v = act ? (av + en[jj]) : NINF;
        float M = v;
#pragma unroll
        for (int off = 32; off >= 1; off >>= 1) M = fmaxf(M, __shfl_xor(M, off));
        unsigned long long msk = __ballot(v == M);
        int cur = __ffsll(msk) - 1;
        s_path[len - 1] = (unsigned char)cur;

        int t = len - 1;
        while (t >= 1) {
            const int n = (t < 8) ? t : 8;
            unsigned r[8];
#pragma unroll
            for (int k = 0; k < 8; ++k)
                r[k] = (k < n) ? (unsigned)s_bp[(size_t)(t - k) * KK + jj] : 0u;
#pragma unroll
            for (int k = 0; k < 8; ++k) {
                if (k < n) {
                    cur = __builtin_amdgcn_readlane((int)r[k], cur);
                    if (lane == 0) s_path[t - k - 1] = (unsigned char)cur;
                }
            }
            t -= n;
        }

        float* ob = out + 1 + (size_t)b * TT;
        for (int tt = lane; tt < TT; tt += 64)
            ob[tt] = (tt < len) ? (float)s_path[tt] : -1.0f;
    }
}

__global__ __launch_bounds__(512) void loss_reduce(const float* __restrict__ ws,
                                                   float* __restrict__ out)
{
    __shared__ float sh[8];
    const int lane = threadIdx.x & 63;
    const int w    = threadIdx.x >> 6;
    float s = ws[threadIdx.x];
#pragma unroll
    for (int off = 32; off >= 1; off >>= 1) s += __shfl_xor(s, off);
    if (lane == 0) sh[w] = s;
    __syncthreads();
    if (threadIdx.x == 0) {
        float tot = 0.f;
        for (int i = 0; i < 8; ++i) tot += sh[i];
        out[0] = -tot;
    }
}

extern "C" void kernel_launch(void* const* d_in, const int* in_sizes, int n_in,
                              void* d_out, int out_size, void* d_ws, size_t ws_size,
                              hipStream_t stream)
{
    const float* em   = (const float*)d_in[0];
    const int*   tags = (const int*)d_in[1];
    const float* st   = (const float*)d_in[2];
    const float* en   = (const float*)d_in[3];
    const float* tr   = (const float*)d_in[4];
    float* out = (float*)d_out;

    const size_t BPBYTES = (size_t)BB * TT * KK;   // 25,165,824
    if (ws_size >= BPBYTES + BB * sizeof(float)) {
        unsigned char* gbp = (unsigned char*)d_ws;
        float* wsl = (float*)((char*)d_ws + BPBYTES);
        hipLaunchKernelGGL(crf_fast, dim3(BB / 4), dim3(512), 0, stream,
                           em, tags, st, en, tr, out, wsl, gbp);
        hipLaunchKernelGGL(loss_reduce, dim3(1), dim3(512), 0, stream, wsl, out);
    } else {
        float* wsf = (float*)d_ws;
        hipLaunchKernelGGL(crf_main, dim3(BB), dim3(128), 0, stream,
                           em, tags, st, en, tr, out, wsf);
        hipLaunchKernelGGL(loss_reduce, dim3(1), dim3(512), 0, stream, wsf, out);
    }
}

// Round 13
// 475.413 us; speedup vs baseline: 1.4034x; 1.4034x over previous
//
#include <hip/hip_runtime.h>

#define BB 512
#define TT 1024
#define KK 48
#define RING 16
#define NINF (-1e30f)

#define CLOBBER() asm volatile("" ::: "memory")

__device__ __forceinline__ float rfirst(float v) {
    return __int_as_float(__builtin_amdgcn_readfirstlane(__float_as_int(v)));
}

// exact max tree over X[48] (identical op sequence everywhere -> bit-exact M)
#define MAXTREE(X, MV) {                                                     \
        float l1[16];                                                        \
        _Pragma("unroll")                                                    \
        for (int q_ = 0; q_ < 16; ++q_)                                      \
            l1[q_] = fmaxf(fmaxf(X[3 * q_], X[3 * q_ + 1]), X[3 * q_ + 2]);  \
        float l2[6];                                                         \
        _Pragma("unroll")                                                    \
        for (int q_ = 0; q_ < 5; ++q_)                                       \
            l2[q_] = fmaxf(fmaxf(l1[3 * q_], l1[3 * q_ + 1]),                \
                           l1[3 * q_ + 2]);                                  \
        l2[5] = l1[15];                                                      \
        MV = fmaxf(fmaxf(fmaxf(l2[0], l2[1]), l2[2]),                        \
                   fmaxf(fmaxf(l2[3], l2[4]), l2[5]));                       \
    }

// X from broadcast row R4 + register column Tc
#define XADDS(R4, X) {                                                       \
        _Pragma("unroll")                                                    \
        for (int q_ = 0; q_ < 12; ++q_) {                                    \
            float4 v_ = R4[q_];                                              \
            X[4 * q_ + 0] = v_.x + Tc[4 * q_ + 0];                           \
            X[4 * q_ + 1] = v_.y + Tc[4 * q_ + 1];                           \
            X[4 * q_ + 2] = v_.z + Tc[4 * q_ + 2];                           \
            X[4 * q_ + 3] = v_.w + Tc[4 * q_ + 3];                           \
        }                                                                    \
    }

// first-occurrence argmax, VGPR-pure: key_i = bits(X_i - M) | i; min-tree
#define ARGKEY(X, MV, BI) {                                                  \
        unsigned u[KK];                                                      \
        _Pragma("unroll")                                                    \
        for (int i_ = 0; i_ < KK; ++i_)                                      \
            u[i_] = (unsigned)__float_as_int(X[i_] - MV) | (unsigned)i_;     \
        unsigned m1[16];                                                     \
        _Pragma("unroll")                                                    \
        for (int q_ = 0; q_ < 16; ++q_)                                      \
            m1[q_] = min(min(u[3 * q_], u[3 * q_ + 1]), u[3 * q_ + 2]);      \
        unsigned m2[6];                                                      \
        _Pragma("unroll")                                                    \
        for (int q_ = 0; q_ < 5; ++q_)                                       \
            m2[q_] = min(min(m1[3 * q_], m1[3 * q_ + 1]), m1[3 * q_ + 2]);   \
        m2[5] = m1[15];                                                      \
        BI = min(min(min(m2[0], m2[1]), m2[2]),                              \
                 min(min(m2[3], m2[4]), m2[5]));                             \
    }

// One 256-thread block per batch:
//   wid0: forward scan (loss partial)         [independent]
//   wid1: viterbi VALUE scan (producer)       [critical serial chain]
//   wid2: argmax+bp for odd steps (consumer)  [parallel over t]
//   wid3: argmax+bp for even steps (consumer) [parallel over t]
// Producer publishes alpha rows in a 16-row LDS ring + flag; consumers
// recompute X/M bit-exactly and store backpointers. 2048 waves -> 2/SIMD.
__global__ __launch_bounds__(256, 2) void crf_pc(
    const float* __restrict__ em, const int* __restrict__ tags,
    const float* __restrict__ st, const float* __restrict__ en,
    const float* __restrict__ tr, float* __restrict__ out,
    float* __restrict__ wsl)
{
    __shared__ unsigned char s_bp[TT * KK];          // 48 KB (row 0 unused)
    __shared__ unsigned char s_path[TT];             // 1 KB
    __shared__ __align__(16) float s_ring[RING][64]; // 4 KB alpha ring
    __shared__ __align__(16) float s_favb[64];       // fwd broadcast
    __shared__ int s_flag, s_c0, s_c1;

    const int b    = blockIdx.x;
    const int tid  = threadIdx.x;
    const int lane = tid & 63;
    const int wid  = tid >> 6;

    const float* emb = em + (size_t)b * TT * KK;
    const int*   tgb = tags + (size_t)b * TT;

    if (tid == 0) { s_flag = -1; s_c0 = 0; s_c1 = 0; }

    // sequence length (contiguous prefix mask)
    int cnt = 0;
    for (int t = lane; t < TT; t += 64) cnt += (tgb[t] > -1) ? 1 : 0;
#pragma unroll
    for (int off = 32; off >= 1; off >>= 1) cnt += __shfl_xor(cnt, off);
    const int len = cnt;  // >= 1

    const bool act = lane < KK;
    const int  jj  = act ? lane : (KK - 1);   // lanes 48-63 mirror lane 47
    const int  S   = len - 1;

    __syncthreads();   // flag/counter init visible to all waves

    float av_final = NINF;   // wid1 carries this to the epilogue

    if (wid == 0) {
        // ================= forward wave: gold score + logZ =================
        float sc = 0.f;
        for (int t = lane; t < len; t += 64) {
            int tg = tgb[t];
            sc += emb[t * KK + tg];
            if (t > 0) sc += tr[tgb[t - 1] * KK + tg];
        }
#pragma unroll
        for (int off = 32; off >= 1; off >>= 1) sc += __shfl_xor(sc, off);
        const float score = sc + st[tgb[0]] + en[tgb[len - 1]];

        float eTc[KK];
#pragma unroll
        for (int i = 0; i < KK; ++i) eTc[i] = __expf(tr[i * KK + jj]);

        float a0 = st[jj] + emb[jj];
        float C  = rfirst(a0);
        float p  = __expf(a0 - C);

        const float4* S4 = (const float4*)(&s_favb[0]);

        float e[2];
        {
            int t1 = (1 < len) ? 1 : (len - 1);
            int t2 = (2 < len) ? 2 : (len - 1);
            e[1] = emb[(size_t)t1 * KK + jj];
            e[0] = emb[(size_t)t2 * KK + jj];
        }

#define FSTEP(t_, RENORM) {                                                  \
        const float eS = e[(t_) & 1];                                        \
        s_favb[lane] = p;              /* DS in-order within wave */         \
        float z0 = 0.f, z1 = 0.f, z2 = 0.f, z3 = 0.f;                        \
        float z4 = 0.f, z5 = 0.f, z6 = 0.f, z7 = 0.f;                        \
        _Pragma("unroll")                                                    \
        for (int q_ = 0; q_ < 6; ++q_) {                                     \
            float4 v0 = S4[2 * q_], v1 = S4[2 * q_ + 1];                     \
            z0 = fmaf(v0.x, eTc[8 * q_ + 0], z0);                            \
            z1 = fmaf(v0.y, eTc[8 * q_ + 1], z1);                            \
            z2 = fmaf(v0.z, eTc[8 * q_ + 2], z2);                            \
            z3 = fmaf(v0.w, eTc[8 * q_ + 3], z3);                            \
            z4 = fmaf(v1.x, eTc[8 * q_ + 4], z4);                            \
            z5 = fmaf(v1.y, eTc[8 * q_ + 5], z5);                            \
            z6 = fmaf(v1.z, eTc[8 * q_ + 6], z6);                            \
            z7 = fmaf(v1.w, eTc[8 * q_ + 7], z7);                            \
        }                                                                    \
        p = (((z0 + z1) + (z2 + z3)) + ((z4 + z5) + (z6 + z7)))              \
            * __expf(eS);                                                    \
        if (RENORM) {                                                        \
            float m_ = rfirst(p);                                            \
            p *= __frcp_rn(m_);                                              \
            C += __logf(m_);                                                 \
        }                                                                    \
        int tn = (t_) + 2; tn = (tn < len) ? tn : (len - 1);                 \
        e[(t_) & 1] = emb[(size_t)tn * KK + jj];                             \
    }
        {
            int t = 1;
            for (; t + 4 <= S + 1; t += 4) {
                FSTEP(t, 0) FSTEP(t + 1, 0) FSTEP(t + 2, 0) FSTEP(t + 3, 1)
            }
            for (; t <= S; ++t) FSTEP(t, 1)
        }
#undef FSTEP

        float y = act ? (p * __expf(en[jj])) : 0.f;
#pragma unroll
        for (int off = 32; off >= 1; off >>= 1) y += __shfl_xor(y, off);
        float logz = C + __logf(y);
        if (lane == 0) wsl[b] = score - logz;
    } else if (wid == 1) {
        // ================= producer: viterbi VALUE scan =================
        __builtin_amdgcn_s_setprio(1);
        float Tc[KK];
#pragma unroll
        for (int i = 0; i < KK; ++i) Tc[i] = tr[i * KK + jj];

        float av = st[jj] + emb[jj];

        // publish row 0 (initial alpha) then flag=0
        *(volatile float*)&s_ring[0][lane] = av;
        CLOBBER();
        if (lane == 0) *(volatile int*)&s_flag = 0;
        CLOBBER();

        float e[2];
        {
            int t1 = (1 < len) ? 1 : (len - 1);
            int t2 = (2 < len) ? 2 : (len - 1);
            e[1] = emb[(size_t)t1 * KK + jj];
            e[0] = emb[(size_t)t2 * KK + jj];
        }

#define PSTEP(t_, PAR) {                                                     \
        const float4* R4 =                                                   \
            (const float4*)(&s_ring[((t_) - 1) & (RING - 1)][0]);            \
        float X[KK];                                                         \
        XADDS(R4, X)                                                         \
        float M; MAXTREE(X, M)                                               \
        av = M + e[PAR];                                                     \
        CLOBBER();                                                           \
        *(volatile float*)&s_ring[(t_) & (RING - 1)][lane] = av;             \
        CLOBBER();                                                           \
        if (lane == 0) *(volatile int*)&s_flag = (t_);                       \
        CLOBBER();                                                           \
        int tn = (t_) + 2; tn = (tn < len) ? tn : (len - 1);                 \
        e[PAR] = emb[(size_t)tn * KK + jj];                                  \
    }

        int t = 1;
        for (; t + 1 <= S; t += 2) {
            if ((t & 7) == 1) {
                // ring-slot reuse guard: all readers of rows overwritten in
                // the next 8 steps must have completed (margin per analysis)
                while (min(*(volatile int*)&s_c0,
                           *(volatile int*)&s_c1) < t - 8)
                    __builtin_amdgcn_s_sleep(1);
                CLOBBER();
            }
            PSTEP(t, 1) PSTEP(t + 1, 0)
        }
        if (t <= S) PSTEP(t, 1)   // t stays odd in this loop
#undef PSTEP
        __builtin_amdgcn_s_setprio(0);
        av_final = av;
    } else {
        // ================= consumers: argmax + backpointers =================
        float Tc[KK];
#pragma unroll
        for (int i = 0; i < KK; ++i) Tc[i] = tr[i * KK + jj];

        const int start = (wid == 2) ? 1 : 2;
        volatile int* cslot = (wid == 2) ? (volatile int*)&s_c0
                                         : (volatile int*)&s_c1;

        for (int tau = start; tau <= S; tau += 2) {
            const int want = tau - 1;
            while (*(volatile int*)&s_flag < want)
                __builtin_amdgcn_s_sleep(1);
            CLOBBER();
            const float4* R4 =
                (const float4*)(&s_ring[(tau - 1) & (RING - 1)][0]);
            float X[KK];
            XADDS(R4, X)
            float M; MAXTREE(X, M)       // bit-exact same M as producer
            unsigned bi; ARGKEY(X, M, bi)
            s_bp[tau * KK + jj] = (unsigned char)bi;   // lanes>=48 dup ln47
            CLOBBER();
            if (lane == 0) *cslot = tau;
            CLOBBER();
        }
    }

    __syncthreads();   // bp complete + visible

    if (wid == 1) {
        // ---- best last tag = argmax(av_final + end), first occurrence ----
        float v = act ? (av_final + en[jj]) : NINF;
        float M = v;
#pragma unroll
        for (int off = 32; off >= 1; off >>= 1) M = fmaxf(M, __shfl_xor(M, off));
        unsigned long long msk = __ballot(v == M);
        int cur = __ffsll(msk) - 1;
        s_path[len - 1] = (unsigned char)cur;

        // register-row backtrack: lane l holds bp[t][l]; serial step is a
        // readlane instead of a dependent LDS load. 8-row batches.
        int t = len - 1;
        while (t >= 1) {
            const int n = (t < 8) ? t : 8;
            unsigned r[8];
#pragma unroll
            for (int k = 0; k < 8; ++k)
                r[k] = (k < n) ? (unsigned)s_bp[(t - k) * KK + jj] : 0u;
#pragma unroll
            for (int k = 0; k < 8; ++k) {
                if (k < n) {
                    cur = __builtin_amdgcn_readlane((int)r[k], cur);
                    if (lane == 0) s_path[t - k - 1] = (unsigned char)cur;
                }
            }
            t -= n;
        }

        float* ob = out + 1 + (size_t)b * TT;
        for (int tt = lane; tt < TT; tt += 64)
            ob[tt] = (tt < len) ? (float)s_path[tt] : -1.0f;
    }
}

__global__ __launch_bounds__(512) void loss_reduce(const float* __restrict__ ws,
                                                   float* __restrict__ out)
{
    __shared__ float sh[8];
    const int lane = threadIdx.x & 63;
    const int w    = threadIdx.x >> 6;
    float s = ws[threadIdx.x];  // B == 512 == blockDim
#pragma unroll
    for (int off = 32; off >= 1; off >>= 1) s += __shfl_xor(s, off);
    if (lane == 0) sh[w] = s;
    __syncthreads();
    if (threadIdx.x == 0) {
        float tot = 0.f;
        for (int i = 0; i < 8; ++i) tot += sh[i];
        out[0] = -tot;
    }
}

extern "C" void kernel_launch(void* const* d_in, const int* in_sizes, int n_in,
                              void* d_out, int out_size, void* d_ws, size_t ws_size,
                              hipStream_t stream)
{
    const float* em   = (const float*)d_in[0];
    const int*   tags = (const int*)d_in[1];
    const float* st   = (const float*)d_in[2];
    const float* en   = (const float*)d_in[3];
    const float* tr   = (const float*)d_in[4];
    float* out = (float*)d_out;
    float* wsl = (float*)d_ws;

    hipLaunchKernelGGL(crf_pc, dim3(BB), dim3(256), 0, stream,
                       em, tags, st, en, tr, out, wsl);
    hipLaunchKernelGGL(loss_reduce, dim3(1), dim3(512), 0, stream, wsl, out);
}